// Round 19
// baseline (495.281 us; speedup 1.0000x reference)
//
#include <hip/hip_runtime.h>
#include <cmath>

// SplineNet: 2x SplineConv(D=128, deg-1 B-spline, 1-D pseudo) + linear head.
// Round 19: r15 structure (164us best; launch_bounds(256,4) — the ONLY clean
// config, (512,*)/( *,6) all spill to 40 VGPR) + degree-sorted node perm:
// counting sort (64 bins) groups equal-degree nodes into waves, cutting the
// lockstep agg's padded-slot waste (~55% -> ~5%). Outputs per-node exact.

typedef __attribute__((ext_vector_type(8))) short bf16x8;
typedef __attribute__((ext_vector_type(4))) float f32x4;

static inline int cdiv(int a, int b) { return (a + b - 1) / b; }

__device__ __forceinline__ float bf2f(unsigned short u) {
  unsigned v = ((unsigned)u) << 16;
  return __builtin_bit_cast(float, v);
}
__device__ __forceinline__ unsigned short f2bf(float f) {
  unsigned u = __builtin_bit_cast(unsigned, f);
  u += 0x7FFFu + ((u >> 16) & 1u);
  return (unsigned short)(u >> 16);
}
__device__ __forceinline__ float elu1(float v) {
  return v > 0.f ? v : (expf(v) - 1.f);
}

__global__ void hist_kernel(const int* __restrict__ ei, int E,
                            int* __restrict__ cnt) {
  int e = blockIdx.x * blockDim.x + threadIdx.x;
  if (e < E) atomicAdd(&cnt[ei[E + e]], 1);
}

// ---- three-phase device-wide exclusive scan over cnt[N] ----
__global__ void scan_partials_kernel(const int* __restrict__ cnt, int N,
                                     int* __restrict__ partials) {
  __shared__ int red[256];
  int base = blockIdx.x * 1024;
  int s = 0;
  for (int i = threadIdx.x; i < 1024; i += 256) {
    int idx = base + i;
    if (idx < N) s += cnt[idx];
  }
  red[threadIdx.x] = s;
  __syncthreads();
  for (int off = 128; off > 0; off >>= 1) {
    if (threadIdx.x < off) red[threadIdx.x] += red[threadIdx.x + off];
    __syncthreads();
  }
  if (threadIdx.x == 0) partials[blockIdx.x] = red[0];
}

__global__ void scan_pscan_kernel(const int* __restrict__ partials, int nb,
                                  int* __restrict__ pscan) {
  __shared__ int tmp[256];
  int t = threadIdx.x;
  int v = (t < nb) ? partials[t] : 0;
  tmp[t] = v;
  __syncthreads();
  for (int off = 1; off < 256; off <<= 1) {
    int u = (t >= off) ? tmp[t - off] : 0;
    __syncthreads();
    tmp[t] += u;
    __syncthreads();
  }
  pscan[t + 1] = tmp[t];
  if (t == 0) pscan[0] = 0;
}

__global__ void scan_apply_kernel(const int* __restrict__ cnt, int N,
                                  const int* __restrict__ pscan, int nb,
                                  int* __restrict__ rowptr, int* __restrict__ cursor) {
  __shared__ int tsum[256];
  int t = threadIdx.x;
  int base = blockIdx.x * 1024 + t * 4;
  int v0 = 0, v1 = 0, v2 = 0, v3 = 0;
  if (base + 0 < N) v0 = cnt[base + 0];
  if (base + 1 < N) v1 = cnt[base + 1];
  if (base + 2 < N) v2 = cnt[base + 2];
  if (base + 3 < N) v3 = cnt[base + 3];
  int s = v0 + v1 + v2 + v3;
  tsum[t] = s;
  __syncthreads();
  for (int off = 1; off < 256; off <<= 1) {
    int u = (t >= off) ? tsum[t - off] : 0;
    __syncthreads();
    tsum[t] += u;
    __syncthreads();
  }
  int excl = pscan[blockIdx.x] + tsum[t] - s;
  if (base + 0 < N) { rowptr[base + 0] = excl; cursor[base + 0] = excl; excl += v0; }
  if (base + 1 < N) { rowptr[base + 1] = excl; cursor[base + 1] = excl; excl += v1; }
  if (base + 2 < N) { rowptr[base + 2] = excl; cursor[base + 2] = excl; excl += v2; }
  if (base + 3 < N) { rowptr[base + 3] = excl; cursor[base + 3] = excl; excl += v3; }
  if (blockIdx.x == 0 && t == 0) rowptr[N] = pscan[nb];
}

// scatter edges into CSR order; pack (src, p) as int2
__global__ void scatter_kernel(const int* __restrict__ ei,
                               const float* __restrict__ ea, int E,
                               int* __restrict__ cursor, int2* __restrict__ es) {
  int e = blockIdx.x * blockDim.x + threadIdx.x;
  if (e < E) {
    int dst = ei[E + e];
    int pos = atomicAdd(&cursor[dst], 1);
    es[pos] = make_int2(ei[e], __float_as_int(ea[e]));
  }
}

// ---- degree counting sort: perm groups equal-degree nodes ----
__global__ void deg_hist_kernel(const int* __restrict__ rowptr, int N,
                                int* __restrict__ bins) {
  int i = blockIdx.x * blockDim.x + threadIdx.x;
  if (i < N) {
    int d = rowptr[i + 1] - rowptr[i];
    atomicAdd(&bins[min(d, 63)], 1);
  }
}

__global__ void deg_scan_kernel(const int* __restrict__ bins,
                                int* __restrict__ binoff) {
  if (threadIdx.x == 0 && blockIdx.x == 0) {
    int s = 0;
    for (int i = 0; i < 64; ++i) { binoff[i] = s; s += bins[i]; }
  }
}

__global__ void deg_scatter_kernel(const int* __restrict__ rowptr, int N,
                                   int* __restrict__ binoff,
                                   int* __restrict__ perm) {
  int i = blockIdx.x * blockDim.x + threadIdx.x;
  if (i < N) {
    int d = rowptr[i + 1] - rowptr[i];
    int pos = atomicAdd(&binoff[min(d, 63)], 1);
    perm[pos] = i;
  }
}

// x (f32 [N][128]) -> compact bf16 xb[N][128]
__global__ void cvt_x_kernel(const float* __restrict__ x,
                             unsigned short* __restrict__ xb, int n4) {
  for (int i = blockIdx.x * blockDim.x + threadIdx.x; i < n4;
       i += gridDim.x * blockDim.x) {
    float4 v = ((const float4*)x)[i];
    ushort4 o;
    o.x = f2bf(v.x); o.y = f2bf(v.y); o.z = f2bf(v.z); o.w = f2bf(v.w);
    ((ushort4*)xb)[i] = o;
  }
}

// Build B in MFMA-fragment order: BtF[frag G][lane][8] where G = ks*8+ni,
// col = ni*16+(lane&15), k = ks*32+(lane>>4)*8+j ; B[k][col] = k<KD?W:root.
__global__ void build_btf_kernel(const float* __restrict__ W,
                                 const float* __restrict__ root,
                                 unsigned short* __restrict__ BtF, int KD, int KT) {
  int idx = blockIdx.x * blockDim.x + threadIdx.x;
  if (idx >= 128 * KT) return;
  int G = idx >> 9;
  int r = idx & 511;
  int lane = r >> 3;
  int j = r & 7;
  int ks = G >> 3;
  int ni = G & 7;
  int col = ni * 16 + (lane & 15);
  int k = ks * 32 + (lane >> 4) * 8 + j;
  float v = (k < KD) ? W[(size_t)k * 128 + col] : root[(size_t)(k - KD) * 128 + col];
  BtF[idx] = f2bf(v);
}

// FUSED layer (r15 + perm): block = 4 waves = 16 PERMUTED nodes (wave's 4
// nodes have near-equal degree -> lockstep padding ~5% not ~55%).
// Agg: 16 lanes/node, lane owns 8 dims, 16B dwordx4 gathers. Then barrier,
// MFMA from LDS (wave = 2 n-frags over 16 rows); outputs scattered via perm.
template <int K, int KT, bool FINAL>
__global__ __launch_bounds__(256, 4) void fused_layer(
    const unsigned short* __restrict__ Xc,
    const int* __restrict__ rowptr, const int2* __restrict__ es,
    const int* __restrict__ perm,
    const unsigned short* __restrict__ BtF,
    const float* __restrict__ bias,
    unsigned short* __restrict__ Hout,
    const float* __restrict__ Wm, const float* __restrict__ bm,
    float* __restrict__ FOut) {
  constexpr int LDK = KT + 8;          // pad keeps rows 16B-aligned, staggers banks
  constexpr int NKS = KT / 32;
  __shared__ unsigned short Asub[16][LDK];
  __shared__ float hred[4][16][2];

  const int w = threadIdx.x >> 6;
  const int lane = threadIdx.x & 63;
  const int lr = lane & 15;
  const int kg = lane >> 4;
  const int node0 = blockIdx.x * 16;

  // ---- agg phase ----
  const int g = lane >> 4;        // node sub-index within wave (0..3)
  const int d16 = lane & 15;      // dim-block: dims d16*8 .. d16*8+7
  const int r = w * 4 + g;        // row in block tile
  const int node = perm[node0 + r];   // N % 16 == 0 (50000/16 exact grid)
  const int beg = rowptr[node];
  const int end = rowptr[node + 1];
  const int deg = end - beg;

  float acc[K][8];
#pragma unroll
  for (int k = 0; k < K; ++k)
#pragma unroll
    for (int j = 0; j < 8; ++j) acc[k][j] = 0.f;

  const int mx = max(max(__shfl(deg, 0), __shfl(deg, 16)),
                     max(__shfl(deg, 32), __shfl(deg, 48)));
  const int lastc = max(end - 1, 0);

  for (int s0 = 0; s0 < mx; s0 += 4) {
    int2 sp[4];
#pragma unroll
    for (int t = 0; t < 4; ++t) sp[t] = es[min(beg + s0 + t, lastc)];
    uint4 rv[4];
#pragma unroll
    for (int t = 0; t < 4; ++t)
      rv[t] = *(const uint4*)(Xc + (size_t)sp[t].x * 128 + d16 * 8);
#pragma unroll
    for (int t = 0; t < 4; ++t) {
      const bool ok = (s0 + t) < deg;
      const float v = ok ? __int_as_float(sp[t].y) * (float)(K - 1) : -2.f;
      float x[8];
      x[0] = __builtin_bit_cast(float, rv[t].x << 16);
      x[1] = __builtin_bit_cast(float, rv[t].x & 0xffff0000u);
      x[2] = __builtin_bit_cast(float, rv[t].y << 16);
      x[3] = __builtin_bit_cast(float, rv[t].y & 0xffff0000u);
      x[4] = __builtin_bit_cast(float, rv[t].z << 16);
      x[5] = __builtin_bit_cast(float, rv[t].z & 0xffff0000u);
      x[6] = __builtin_bit_cast(float, rv[t].w << 16);
      x[7] = __builtin_bit_cast(float, rv[t].w & 0xffff0000u);
#pragma unroll
      for (int k = 0; k < K; ++k) {
        const float wk = fmaxf(1.f - fabsf(v - (float)k), 0.f);
#pragma unroll
        for (int j = 0; j < 8; ++j) acc[k][j] = fmaf(wk, x[j], acc[k][j]);
      }
    }
  }

  const float sc = 1.f / fmaxf((float)deg, 1.f);
#pragma unroll
  for (int k = 0; k < K; ++k) {
    uint4 ov;
    ov.x = (unsigned)f2bf(acc[k][0] * sc) | ((unsigned)f2bf(acc[k][1] * sc) << 16);
    ov.y = (unsigned)f2bf(acc[k][2] * sc) | ((unsigned)f2bf(acc[k][3] * sc) << 16);
    ov.z = (unsigned)f2bf(acc[k][4] * sc) | ((unsigned)f2bf(acc[k][5] * sc) << 16);
    ov.w = (unsigned)f2bf(acc[k][6] * sc) | ((unsigned)f2bf(acc[k][7] * sc) << 16);
    *(uint4*)&Asub[r][k * 128 + d16 * 8] = ov;
  }
  // own row (root term): 16B copy
  uint4 ownv = *(const uint4*)(Xc + (size_t)node * 128 + d16 * 8);
  *(uint4*)&Asub[r][K * 128 + d16 * 8] = ownv;
  __syncthreads();

  // ---- MFMA phase: wave w owns cols ni0*16 .. +32 (2 n-frags) ----
  const int ni0 = w * 2;
  f32x4 acc2[2];
  acc2[0] = {0.f, 0.f, 0.f, 0.f};
  acc2[1] = {0.f, 0.f, 0.f, 0.f};
#pragma unroll
  for (int ks = 0; ks < NKS; ++ks) {
    bf16x8 a = *(const bf16x8*)&Asub[lr][ks * 32 + kg * 8];
#pragma unroll
    for (int j = 0; j < 2; ++j) {
      bf16x8 b = *(const bf16x8*)(BtF + (size_t)(ks * 8 + ni0 + j) * 512 + lane * 8);
      acc2[j] = __builtin_amdgcn_mfma_f32_16x16x32_bf16(a, b, acc2[j], 0, 0, 0);
    }
  }

  float bv[2];
#pragma unroll
  for (int j = 0; j < 2; ++j) bv[j] = bias[(ni0 + j) * 16 + lr];

  if constexpr (!FINAL) {
#pragma unroll
    for (int rr = 0; rr < 4; ++rr) {
      int row = kg * 4 + rr;
      int onode = perm[node0 + row];
#pragma unroll
      for (int j = 0; j < 2; ++j) {
        float h = elu1(acc2[j][rr] + bv[j]);
        Hout[(size_t)onode * 128 + (ni0 + j) * 16 + lr] = f2bf(h);
      }
    }
  } else {
    float wm0[2], wm1[2];
#pragma unroll
    for (int j = 0; j < 2; ++j) {
      float2 wv = *(const float2*)&Wm[((ni0 + j) * 16 + lr) * 2];
      wm0[j] = wv.x; wm1[j] = wv.y;
    }
#pragma unroll
    for (int rr = 0; rr < 4; ++rr) {
      int row = kg * 4 + rr;
      float t0 = 0.f, t1 = 0.f;
#pragma unroll
      for (int j = 0; j < 2; ++j) {
        float h = elu1(acc2[j][rr] + bv[j]);
        t0 = fmaf(h, wm0[j], t0);
        t1 = fmaf(h, wm1[j], t1);
      }
#pragma unroll
      for (int off = 8; off > 0; off >>= 1) {
        t0 += __shfl_down(t0, off);
        t1 += __shfl_down(t1, off);
      }
      if (lr == 0) {
        hred[w][row][0] = t0;
        hred[w][row][1] = t1;
      }
    }
    __syncthreads();
    if (threadIdx.x < 32) {
      int row = threadIdx.x >> 1;
      int c = threadIdx.x & 1;
      int onode = perm[node0 + row];
      float s = hred[0][row][c] + hred[1][row][c] + hred[2][row][c] +
                hred[3][row][c] + bm[c];
      FOut[(size_t)onode * 2 + c] = fmaxf(s, 0.f);
    }
  }
}

extern "C" void kernel_launch(void* const* d_in, const int* in_sizes, int n_in,
                              void* d_out, int out_size, void* d_ws, size_t ws_size,
                              hipStream_t stream) {
  const float* x = (const float*)d_in[0];
  const int* ei = (const int*)d_in[1];
  const float* ea = (const float*)d_in[2];
  const float* W1 = (const float*)d_in[3];
  const float* root1 = (const float*)d_in[4];
  const float* b1 = (const float*)d_in[5];
  const float* W2 = (const float*)d_in[6];
  const float* root2 = (const float*)d_in[7];
  const float* b2 = (const float*)d_in[8];
  const float* Wm = (const float*)d_in[9];
  const float* bm = (const float*)d_in[10];
  const int N = in_sizes[0] / 128;
  const int E = in_sizes[2];
  const int KT1 = 512, KT2 = 768;
  const int nb = cdiv(N, 1024);

  char* base = (char*)d_ws;
  size_t off = 0;
  auto alloc = [&](size_t bytes) -> void* {
    void* p = base + off;
    off += (bytes + 255) & ~(size_t)255;
    return p;
  };
  int* cnt = (int*)alloc((size_t)N * 4);
  int* rowptr = (int*)alloc((size_t)(N + 1) * 4);
  int* cursor = (int*)alloc((size_t)N * 4);
  int* partials = (int*)alloc(256 * 4);
  int* pscan = (int*)alloc(257 * 4);
  int* bins = (int*)alloc(64 * 4);
  int* binoff = (int*)alloc(64 * 4);
  int* perm = (int*)alloc((size_t)N * 4);
  int2* es = (int2*)alloc((size_t)E * 8);
  unsigned short* xb = (unsigned short*)alloc((size_t)N * 128 * 2);
  unsigned short* h1 = (unsigned short*)alloc((size_t)N * 128 * 2);
  unsigned short* BtF1 = (unsigned short*)alloc((size_t)128 * KT1 * 2);
  unsigned short* BtF2 = (unsigned short*)alloc((size_t)128 * KT2 * 2);
  (void)ws_size; (void)n_in; (void)out_size;

  // CSR build (dst bins)
  hipMemsetAsync(cnt, 0, (size_t)N * 4, stream);
  hipMemsetAsync(bins, 0, 64 * 4, stream);
  hist_kernel<<<cdiv(E, 256), 256, 0, stream>>>(ei, E, cnt);
  scan_partials_kernel<<<nb, 256, 0, stream>>>(cnt, N, partials);
  scan_pscan_kernel<<<1, 256, 0, stream>>>(partials, nb, pscan);
  scan_apply_kernel<<<nb, 256, 0, stream>>>(cnt, N, pscan, nb, rowptr, cursor);
  scatter_kernel<<<cdiv(E, 256), 256, 0, stream>>>(ei, ea, E, cursor, es);

  // degree-sorted node permutation (shared by both layers)
  deg_hist_kernel<<<cdiv(N, 256), 256, 0, stream>>>(rowptr, N, bins);
  deg_scan_kernel<<<1, 64, 0, stream>>>(bins, binoff);
  deg_scatter_kernel<<<cdiv(N, 256), 256, 0, stream>>>(rowptr, N, binoff, perm);

  // weights -> fragment-order bf16
  build_btf_kernel<<<cdiv(128 * KT1, 256), 256, 0, stream>>>(W1, root1, BtF1, 384, KT1);
  build_btf_kernel<<<cdiv(128 * KT2, 256), 256, 0, stream>>>(W2, root2, BtF2, 640, KT2);

  // x -> compact bf16 xb
  cvt_x_kernel<<<2048, 256, 0, stream>>>(x, xb, N * 32);

  const int nblk = N / 16;  // 50000/16 = 3125 exact
  // layer 1 (K=3): fused agg+GEMM -> compact h1
  fused_layer<3, 512, false><<<nblk, 256, 0, stream>>>(
      xb, rowptr, es, perm, BtF1, b1, h1, nullptr, nullptr, nullptr);
  // layer 2 (K=5): fused agg+GEMM+head -> out
  fused_layer<5, 768, true><<<nblk, 256, 0, stream>>>(
      h1, rowptr, es, perm, BtF2, b2, nullptr, Wm, bm, (float*)d_out);
}

// Round 20
// 172.947 us; speedup vs baseline: 2.8638x; 2.8638x over previous
//
#include <hip/hip_runtime.h>
#include <cmath>

// SplineNet: 2x SplineConv(D=128, deg-1 B-spline, 1-D pseudo) + linear head.
// Round 20: r19 pipeline with CONTENTION-FREE degree sort. r19's deg_hist/
// deg_scatter did 50K global atomics onto ~15 hot bins -> 2x165us serial
// stalls (VALUBusy 0.007%). Now per-block LDS aggregation: 64 global
// atomics/block. Fused kernels unchanged (perm effect finally measurable).

typedef __attribute__((ext_vector_type(8))) short bf16x8;
typedef __attribute__((ext_vector_type(4))) float f32x4;

static inline int cdiv(int a, int b) { return (a + b - 1) / b; }

__device__ __forceinline__ float bf2f(unsigned short u) {
  unsigned v = ((unsigned)u) << 16;
  return __builtin_bit_cast(float, v);
}
__device__ __forceinline__ unsigned short f2bf(float f) {
  unsigned u = __builtin_bit_cast(unsigned, f);
  u += 0x7FFFu + ((u >> 16) & 1u);
  return (unsigned short)(u >> 16);
}
__device__ __forceinline__ float elu1(float v) {
  return v > 0.f ? v : (expf(v) - 1.f);
}

__global__ void hist_kernel(const int* __restrict__ ei, int E,
                            int* __restrict__ cnt) {
  int e = blockIdx.x * blockDim.x + threadIdx.x;
  if (e < E) atomicAdd(&cnt[ei[E + e]], 1);
}

// ---- three-phase device-wide exclusive scan over cnt[N] ----
__global__ void scan_partials_kernel(const int* __restrict__ cnt, int N,
                                     int* __restrict__ partials) {
  __shared__ int red[256];
  int base = blockIdx.x * 1024;
  int s = 0;
  for (int i = threadIdx.x; i < 1024; i += 256) {
    int idx = base + i;
    if (idx < N) s += cnt[idx];
  }
  red[threadIdx.x] = s;
  __syncthreads();
  for (int off = 128; off > 0; off >>= 1) {
    if (threadIdx.x < off) red[threadIdx.x] += red[threadIdx.x + off];
    __syncthreads();
  }
  if (threadIdx.x == 0) partials[blockIdx.x] = red[0];
}

__global__ void scan_pscan_kernel(const int* __restrict__ partials, int nb,
                                  int* __restrict__ pscan) {
  __shared__ int tmp[256];
  int t = threadIdx.x;
  int v = (t < nb) ? partials[t] : 0;
  tmp[t] = v;
  __syncthreads();
  for (int off = 1; off < 256; off <<= 1) {
    int u = (t >= off) ? tmp[t - off] : 0;
    __syncthreads();
    tmp[t] += u;
    __syncthreads();
  }
  pscan[t + 1] = tmp[t];
  if (t == 0) pscan[0] = 0;
}

__global__ void scan_apply_kernel(const int* __restrict__ cnt, int N,
                                  const int* __restrict__ pscan, int nb,
                                  int* __restrict__ rowptr, int* __restrict__ cursor) {
  __shared__ int tsum[256];
  int t = threadIdx.x;
  int base = blockIdx.x * 1024 + t * 4;
  int v0 = 0, v1 = 0, v2 = 0, v3 = 0;
  if (base + 0 < N) v0 = cnt[base + 0];
  if (base + 1 < N) v1 = cnt[base + 1];
  if (base + 2 < N) v2 = cnt[base + 2];
  if (base + 3 < N) v3 = cnt[base + 3];
  int s = v0 + v1 + v2 + v3;
  tsum[t] = s;
  __syncthreads();
  for (int off = 1; off < 256; off <<= 1) {
    int u = (t >= off) ? tsum[t - off] : 0;
    __syncthreads();
    tsum[t] += u;
    __syncthreads();
  }
  int excl = pscan[blockIdx.x] + tsum[t] - s;
  if (base + 0 < N) { rowptr[base + 0] = excl; cursor[base + 0] = excl; excl += v0; }
  if (base + 1 < N) { rowptr[base + 1] = excl; cursor[base + 1] = excl; excl += v1; }
  if (base + 2 < N) { rowptr[base + 2] = excl; cursor[base + 2] = excl; excl += v2; }
  if (base + 3 < N) { rowptr[base + 3] = excl; cursor[base + 3] = excl; excl += v3; }
  if (blockIdx.x == 0 && t == 0) rowptr[N] = pscan[nb];
}

// scatter edges into CSR order; pack (src, p) as int2
__global__ void scatter_kernel(const int* __restrict__ ei,
                               const float* __restrict__ ea, int E,
                               int* __restrict__ cursor, int2* __restrict__ es) {
  int e = blockIdx.x * blockDim.x + threadIdx.x;
  if (e < E) {
    int dst = ei[E + e];
    int pos = atomicAdd(&cursor[dst], 1);
    es[pos] = make_int2(ei[e], __float_as_int(ea[e]));
  }
}

// ---- degree counting sort (contention-free: per-block LDS aggregation) ----
__global__ void deg_hist_kernel(const int* __restrict__ rowptr, int N,
                                int* __restrict__ bins) {
  __shared__ int lb[64];
  if (threadIdx.x < 64) lb[threadIdx.x] = 0;
  __syncthreads();
  int i = blockIdx.x * blockDim.x + threadIdx.x;
  if (i < N) {
    int d = rowptr[i + 1] - rowptr[i];
    atomicAdd(&lb[min(d, 63)], 1);
  }
  __syncthreads();
  if (threadIdx.x < 64 && lb[threadIdx.x] > 0)
    atomicAdd(&bins[threadIdx.x], lb[threadIdx.x]);
}

__global__ void deg_scan_kernel(const int* __restrict__ bins,
                                int* __restrict__ binoff) {
  if (threadIdx.x == 0 && blockIdx.x == 0) {
    int s = 0;
    for (int i = 0; i < 64; ++i) { binoff[i] = s; s += bins[i]; }
  }
}

// local position via LDS atomic, one global range-reservation per bin/block
__global__ void deg_scatter_kernel(const int* __restrict__ rowptr, int N,
                                   int* __restrict__ binoff,
                                   int* __restrict__ perm) {
  __shared__ int lcnt[64];
  __shared__ int gbase[64];
  if (threadIdx.x < 64) lcnt[threadIdx.x] = 0;
  __syncthreads();
  int i = blockIdx.x * blockDim.x + threadIdx.x;
  int bin = 0, lpos = 0;
  if (i < N) {
    bin = min(rowptr[i + 1] - rowptr[i], 63);
    lpos = atomicAdd(&lcnt[bin], 1);
  }
  __syncthreads();
  if (threadIdx.x < 64 && lcnt[threadIdx.x] > 0)
    gbase[threadIdx.x] = atomicAdd(&binoff[threadIdx.x], lcnt[threadIdx.x]);
  __syncthreads();
  if (i < N) perm[gbase[bin] + lpos] = i;
}

// x (f32 [N][128]) -> compact bf16 xb[N][128]
__global__ void cvt_x_kernel(const float* __restrict__ x,
                             unsigned short* __restrict__ xb, int n4) {
  for (int i = blockIdx.x * blockDim.x + threadIdx.x; i < n4;
       i += gridDim.x * blockDim.x) {
    float4 v = ((const float4*)x)[i];
    ushort4 o;
    o.x = f2bf(v.x); o.y = f2bf(v.y); o.z = f2bf(v.z); o.w = f2bf(v.w);
    ((ushort4*)xb)[i] = o;
  }
}

// Build B in MFMA-fragment order: BtF[frag G][lane][8] where G = ks*8+ni,
// col = ni*16+(lane&15), k = ks*32+(lane>>4)*8+j ; B[k][col] = k<KD?W:root.
__global__ void build_btf_kernel(const float* __restrict__ W,
                                 const float* __restrict__ root,
                                 unsigned short* __restrict__ BtF, int KD, int KT) {
  int idx = blockIdx.x * blockDim.x + threadIdx.x;
  if (idx >= 128 * KT) return;
  int G = idx >> 9;
  int r = idx & 511;
  int lane = r >> 3;
  int j = r & 7;
  int ks = G >> 3;
  int ni = G & 7;
  int col = ni * 16 + (lane & 15);
  int k = ks * 32 + (lane >> 4) * 8 + j;
  float v = (k < KD) ? W[(size_t)k * 128 + col] : root[(size_t)(k - KD) * 128 + col];
  BtF[idx] = f2bf(v);
}

// FUSED layer (r15 + perm): block = 4 waves = 16 PERMUTED nodes (wave's 4
// nodes have near-equal degree -> lockstep padding ~5% not ~55%).
// Agg: 16 lanes/node, lane owns 8 dims, 16B dwordx4 gathers. Then barrier,
// MFMA from LDS (wave = 2 n-frags over 16 rows); outputs scattered via perm.
template <int K, int KT, bool FINAL>
__global__ __launch_bounds__(256, 4) void fused_layer(
    const unsigned short* __restrict__ Xc,
    const int* __restrict__ rowptr, const int2* __restrict__ es,
    const int* __restrict__ perm,
    const unsigned short* __restrict__ BtF,
    const float* __restrict__ bias,
    unsigned short* __restrict__ Hout,
    const float* __restrict__ Wm, const float* __restrict__ bm,
    float* __restrict__ FOut) {
  constexpr int LDK = KT + 8;          // pad keeps rows 16B-aligned, staggers banks
  constexpr int NKS = KT / 32;
  __shared__ unsigned short Asub[16][LDK];
  __shared__ float hred[4][16][2];

  const int w = threadIdx.x >> 6;
  const int lane = threadIdx.x & 63;
  const int lr = lane & 15;
  const int kg = lane >> 4;
  const int node0 = blockIdx.x * 16;

  // ---- agg phase ----
  const int g = lane >> 4;        // node sub-index within wave (0..3)
  const int d16 = lane & 15;      // dim-block: dims d16*8 .. d16*8+7
  const int r = w * 4 + g;        // row in block tile
  const int node = perm[node0 + r];   // N % 16 == 0 (50000/16 exact grid)
  const int beg = rowptr[node];
  const int end = rowptr[node + 1];
  const int deg = end - beg;

  float acc[K][8];
#pragma unroll
  for (int k = 0; k < K; ++k)
#pragma unroll
    for (int j = 0; j < 8; ++j) acc[k][j] = 0.f;

  const int mx = max(max(__shfl(deg, 0), __shfl(deg, 16)),
                     max(__shfl(deg, 32), __shfl(deg, 48)));
  const int lastc = max(end - 1, 0);

  for (int s0 = 0; s0 < mx; s0 += 4) {
    int2 sp[4];
#pragma unroll
    for (int t = 0; t < 4; ++t) sp[t] = es[min(beg + s0 + t, lastc)];
    uint4 rv[4];
#pragma unroll
    for (int t = 0; t < 4; ++t)
      rv[t] = *(const uint4*)(Xc + (size_t)sp[t].x * 128 + d16 * 8);
#pragma unroll
    for (int t = 0; t < 4; ++t) {
      const bool ok = (s0 + t) < deg;
      const float v = ok ? __int_as_float(sp[t].y) * (float)(K - 1) : -2.f;
      float x[8];
      x[0] = __builtin_bit_cast(float, rv[t].x << 16);
      x[1] = __builtin_bit_cast(float, rv[t].x & 0xffff0000u);
      x[2] = __builtin_bit_cast(float, rv[t].y << 16);
      x[3] = __builtin_bit_cast(float, rv[t].y & 0xffff0000u);
      x[4] = __builtin_bit_cast(float, rv[t].z << 16);
      x[5] = __builtin_bit_cast(float, rv[t].z & 0xffff0000u);
      x[6] = __builtin_bit_cast(float, rv[t].w << 16);
      x[7] = __builtin_bit_cast(float, rv[t].w & 0xffff0000u);
#pragma unroll
      for (int k = 0; k < K; ++k) {
        const float wk = fmaxf(1.f - fabsf(v - (float)k), 0.f);
#pragma unroll
        for (int j = 0; j < 8; ++j) acc[k][j] = fmaf(wk, x[j], acc[k][j]);
      }
    }
  }

  const float sc = 1.f / fmaxf((float)deg, 1.f);
#pragma unroll
  for (int k = 0; k < K; ++k) {
    uint4 ov;
    ov.x = (unsigned)f2bf(acc[k][0] * sc) | ((unsigned)f2bf(acc[k][1] * sc) << 16);
    ov.y = (unsigned)f2bf(acc[k][2] * sc) | ((unsigned)f2bf(acc[k][3] * sc) << 16);
    ov.z = (unsigned)f2bf(acc[k][4] * sc) | ((unsigned)f2bf(acc[k][5] * sc) << 16);
    ov.w = (unsigned)f2bf(acc[k][6] * sc) | ((unsigned)f2bf(acc[k][7] * sc) << 16);
    *(uint4*)&Asub[r][k * 128 + d16 * 8] = ov;
  }
  // own row (root term): 16B copy
  uint4 ownv = *(const uint4*)(Xc + (size_t)node * 128 + d16 * 8);
  *(uint4*)&Asub[r][K * 128 + d16 * 8] = ownv;
  __syncthreads();

  // ---- MFMA phase: wave w owns cols ni0*16 .. +32 (2 n-frags) ----
  const int ni0 = w * 2;
  f32x4 acc2[2];
  acc2[0] = {0.f, 0.f, 0.f, 0.f};
  acc2[1] = {0.f, 0.f, 0.f, 0.f};
#pragma unroll
  for (int ks = 0; ks < NKS; ++ks) {
    bf16x8 a = *(const bf16x8*)&Asub[lr][ks * 32 + kg * 8];
#pragma unroll
    for (int j = 0; j < 2; ++j) {
      bf16x8 b = *(const bf16x8*)(BtF + (size_t)(ks * 8 + ni0 + j) * 512 + lane * 8);
      acc2[j] = __builtin_amdgcn_mfma_f32_16x16x32_bf16(a, b, acc2[j], 0, 0, 0);
    }
  }

  float bv[2];
#pragma unroll
  for (int j = 0; j < 2; ++j) bv[j] = bias[(ni0 + j) * 16 + lr];

  if constexpr (!FINAL) {
#pragma unroll
    for (int rr = 0; rr < 4; ++rr) {
      int row = kg * 4 + rr;
      int onode = perm[node0 + row];
#pragma unroll
      for (int j = 0; j < 2; ++j) {
        float h = elu1(acc2[j][rr] + bv[j]);
        Hout[(size_t)onode * 128 + (ni0 + j) * 16 + lr] = f2bf(h);
      }
    }
  } else {
    float wm0[2], wm1[2];
#pragma unroll
    for (int j = 0; j < 2; ++j) {
      float2 wv = *(const float2*)&Wm[((ni0 + j) * 16 + lr) * 2];
      wm0[j] = wv.x; wm1[j] = wv.y;
    }
#pragma unroll
    for (int rr = 0; rr < 4; ++rr) {
      int row = kg * 4 + rr;
      float t0 = 0.f, t1 = 0.f;
#pragma unroll
      for (int j = 0; j < 2; ++j) {
        float h = elu1(acc2[j][rr] + bv[j]);
        t0 = fmaf(h, wm0[j], t0);
        t1 = fmaf(h, wm1[j], t1);
      }
#pragma unroll
      for (int off = 8; off > 0; off >>= 1) {
        t0 += __shfl_down(t0, off);
        t1 += __shfl_down(t1, off);
      }
      if (lr == 0) {
        hred[w][row][0] = t0;
        hred[w][row][1] = t1;
      }
    }
    __syncthreads();
    if (threadIdx.x < 32) {
      int row = threadIdx.x >> 1;
      int c = threadIdx.x & 1;
      int onode = perm[node0 + row];
      float s = hred[0][row][c] + hred[1][row][c] + hred[2][row][c] +
                hred[3][row][c] + bm[c];
      FOut[(size_t)onode * 2 + c] = fmaxf(s, 0.f);
    }
  }
}

extern "C" void kernel_launch(void* const* d_in, const int* in_sizes, int n_in,
                              void* d_out, int out_size, void* d_ws, size_t ws_size,
                              hipStream_t stream) {
  const float* x = (const float*)d_in[0];
  const int* ei = (const int*)d_in[1];
  const float* ea = (const float*)d_in[2];
  const float* W1 = (const float*)d_in[3];
  const float* root1 = (const float*)d_in[4];
  const float* b1 = (const float*)d_in[5];
  const float* W2 = (const float*)d_in[6];
  const float* root2 = (const float*)d_in[7];
  const float* b2 = (const float*)d_in[8];
  const float* Wm = (const float*)d_in[9];
  const float* bm = (const float*)d_in[10];
  const int N = in_sizes[0] / 128;
  const int E = in_sizes[2];
  const int KT1 = 512, KT2 = 768;
  const int nb = cdiv(N, 1024);

  char* base = (char*)d_ws;
  size_t off = 0;
  auto alloc = [&](size_t bytes) -> void* {
    void* p = base + off;
    off += (bytes + 255) & ~(size_t)255;
    return p;
  };
  int* cnt = (int*)alloc((size_t)N * 4);
  int* rowptr = (int*)alloc((size_t)(N + 1) * 4);
  int* cursor = (int*)alloc((size_t)N * 4);
  int* partials = (int*)alloc(256 * 4);
  int* pscan = (int*)alloc(257 * 4);
  int* bins = (int*)alloc(64 * 4);
  int* binoff = (int*)alloc(64 * 4);
  int* perm = (int*)alloc((size_t)N * 4);
  int2* es = (int2*)alloc((size_t)E * 8);
  unsigned short* xb = (unsigned short*)alloc((size_t)N * 128 * 2);
  unsigned short* h1 = (unsigned short*)alloc((size_t)N * 128 * 2);
  unsigned short* BtF1 = (unsigned short*)alloc((size_t)128 * KT1 * 2);
  unsigned short* BtF2 = (unsigned short*)alloc((size_t)128 * KT2 * 2);
  (void)ws_size; (void)n_in; (void)out_size;

  // CSR build (dst bins)
  hipMemsetAsync(cnt, 0, (size_t)N * 4, stream);
  hipMemsetAsync(bins, 0, 64 * 4, stream);
  hist_kernel<<<cdiv(E, 256), 256, 0, stream>>>(ei, E, cnt);
  scan_partials_kernel<<<nb, 256, 0, stream>>>(cnt, N, partials);
  scan_pscan_kernel<<<1, 256, 0, stream>>>(partials, nb, pscan);
  scan_apply_kernel<<<nb, 256, 0, stream>>>(cnt, N, pscan, nb, rowptr, cursor);
  scatter_kernel<<<cdiv(E, 256), 256, 0, stream>>>(ei, ea, E, cursor, es);

  // degree-sorted node permutation (shared by both layers)
  deg_hist_kernel<<<cdiv(N, 256), 256, 0, stream>>>(rowptr, N, bins);
  deg_scan_kernel<<<1, 64, 0, stream>>>(bins, binoff);
  deg_scatter_kernel<<<cdiv(N, 256), 256, 0, stream>>>(rowptr, N, binoff, perm);

  // weights -> fragment-order bf16
  build_btf_kernel<<<cdiv(128 * KT1, 256), 256, 0, stream>>>(W1, root1, BtF1, 384, KT1);
  build_btf_kernel<<<cdiv(128 * KT2, 256), 256, 0, stream>>>(W2, root2, BtF2, 640, KT2);

  // x -> compact bf16 xb
  cvt_x_kernel<<<2048, 256, 0, stream>>>(x, xb, N * 32);

  const int nblk = N / 16;  // 50000/16 = 3125 exact
  // layer 1 (K=3): fused agg+GEMM -> compact h1
  fused_layer<3, 512, false><<<nblk, 256, 0, stream>>>(
      xb, rowptr, es, perm, BtF1, b1, h1, nullptr, nullptr, nullptr);
  // layer 2 (K=5): fused agg+GEMM+head -> out
  fused_layer<5, 768, true><<<nblk, 256, 0, stream>>>(
      h1, rowptr, es, perm, BtF2, b2, nullptr, Wm, bm, (float*)d_out);
}

// Round 21
// 163.894 us; speedup vs baseline: 3.0220x; 1.0552x over previous
//
#include <hip/hip_runtime.h>
#include <cmath>

// SplineNet: 2x SplineConv(D=128, deg-1 B-spline, 1-D pseudo) + linear head.
// FINAL (r15 restored, session best 164us): fused agg+GEMM per layer.
//  - agg: wave = 4 nodes simultaneously, 16 lanes/node, 16B dwordx4 gathers
//    (16 addresses/edge -> TA-bound floor), lockstep over max-degree
//  - MFMA from LDS tile (wave = 2 n-frags x 16 rows), BtF fragment-ordered
//  - layer2 fuses the linear head via cross-wave LDS reduce
// Closed avenues (measured): 512-thr / min-waves>=6 launch bounds -> 40-VGPR
// spill (4/4 attempts); 32-row tiles -> occupancy collapse; degree-sort perm
// -> fused -5% but es-locality +FETCH wash (r20).

typedef __attribute__((ext_vector_type(8))) short bf16x8;
typedef __attribute__((ext_vector_type(4))) float f32x4;

static inline int cdiv(int a, int b) { return (a + b - 1) / b; }

__device__ __forceinline__ float bf2f(unsigned short u) {
  unsigned v = ((unsigned)u) << 16;
  return __builtin_bit_cast(float, v);
}
__device__ __forceinline__ unsigned short f2bf(float f) {
  unsigned u = __builtin_bit_cast(unsigned, f);
  u += 0x7FFFu + ((u >> 16) & 1u);
  return (unsigned short)(u >> 16);
}
__device__ __forceinline__ float elu1(float v) {
  return v > 0.f ? v : (expf(v) - 1.f);
}

__global__ void hist_kernel(const int* __restrict__ ei, int E,
                            int* __restrict__ cnt) {
  int e = blockIdx.x * blockDim.x + threadIdx.x;
  if (e < E) atomicAdd(&cnt[ei[E + e]], 1);
}

// ---- three-phase device-wide exclusive scan over cnt[N] ----
__global__ void scan_partials_kernel(const int* __restrict__ cnt, int N,
                                     int* __restrict__ partials) {
  __shared__ int red[256];
  int base = blockIdx.x * 1024;
  int s = 0;
  for (int i = threadIdx.x; i < 1024; i += 256) {
    int idx = base + i;
    if (idx < N) s += cnt[idx];
  }
  red[threadIdx.x] = s;
  __syncthreads();
  for (int off = 128; off > 0; off >>= 1) {
    if (threadIdx.x < off) red[threadIdx.x] += red[threadIdx.x + off];
    __syncthreads();
  }
  if (threadIdx.x == 0) partials[blockIdx.x] = red[0];
}

__global__ void scan_pscan_kernel(const int* __restrict__ partials, int nb,
                                  int* __restrict__ pscan) {
  __shared__ int tmp[256];
  int t = threadIdx.x;
  int v = (t < nb) ? partials[t] : 0;
  tmp[t] = v;
  __syncthreads();
  for (int off = 1; off < 256; off <<= 1) {
    int u = (t >= off) ? tmp[t - off] : 0;
    __syncthreads();
    tmp[t] += u;
    __syncthreads();
  }
  pscan[t + 1] = tmp[t];
  if (t == 0) pscan[0] = 0;
}

__global__ void scan_apply_kernel(const int* __restrict__ cnt, int N,
                                  const int* __restrict__ pscan, int nb,
                                  int* __restrict__ rowptr, int* __restrict__ cursor) {
  __shared__ int tsum[256];
  int t = threadIdx.x;
  int base = blockIdx.x * 1024 + t * 4;
  int v0 = 0, v1 = 0, v2 = 0, v3 = 0;
  if (base + 0 < N) v0 = cnt[base + 0];
  if (base + 1 < N) v1 = cnt[base + 1];
  if (base + 2 < N) v2 = cnt[base + 2];
  if (base + 3 < N) v3 = cnt[base + 3];
  int s = v0 + v1 + v2 + v3;
  tsum[t] = s;
  __syncthreads();
  for (int off = 1; off < 256; off <<= 1) {
    int u = (t >= off) ? tsum[t - off] : 0;
    __syncthreads();
    tsum[t] += u;
    __syncthreads();
  }
  int excl = pscan[blockIdx.x] + tsum[t] - s;
  if (base + 0 < N) { rowptr[base + 0] = excl; cursor[base + 0] = excl; excl += v0; }
  if (base + 1 < N) { rowptr[base + 1] = excl; cursor[base + 1] = excl; excl += v1; }
  if (base + 2 < N) { rowptr[base + 2] = excl; cursor[base + 2] = excl; excl += v2; }
  if (base + 3 < N) { rowptr[base + 3] = excl; cursor[base + 3] = excl; excl += v3; }
  if (blockIdx.x == 0 && t == 0) rowptr[N] = pscan[nb];
}

// scatter edges into CSR order; pack (src, p) as int2
__global__ void scatter_kernel(const int* __restrict__ ei,
                               const float* __restrict__ ea, int E,
                               int* __restrict__ cursor, int2* __restrict__ es) {
  int e = blockIdx.x * blockDim.x + threadIdx.x;
  if (e < E) {
    int dst = ei[E + e];
    int pos = atomicAdd(&cursor[dst], 1);
    es[pos] = make_int2(ei[e], __float_as_int(ea[e]));
  }
}

// x (f32 [N][128]) -> compact bf16 xb[N][128]
__global__ void cvt_x_kernel(const float* __restrict__ x,
                             unsigned short* __restrict__ xb, int n4) {
  for (int i = blockIdx.x * blockDim.x + threadIdx.x; i < n4;
       i += gridDim.x * blockDim.x) {
    float4 v = ((const float4*)x)[i];
    ushort4 o;
    o.x = f2bf(v.x); o.y = f2bf(v.y); o.z = f2bf(v.z); o.w = f2bf(v.w);
    ((ushort4*)xb)[i] = o;
  }
}

// Build B in MFMA-fragment order: BtF[frag G][lane][8] where G = ks*8+ni,
// col = ni*16+(lane&15), k = ks*32+(lane>>4)*8+j ; B[k][col] = k<KD?W:root.
__global__ void build_btf_kernel(const float* __restrict__ W,
                                 const float* __restrict__ root,
                                 unsigned short* __restrict__ BtF, int KD, int KT) {
  int idx = blockIdx.x * blockDim.x + threadIdx.x;
  if (idx >= 128 * KT) return;
  int G = idx >> 9;
  int r = idx & 511;
  int lane = r >> 3;
  int j = r & 7;
  int ks = G >> 3;
  int ni = G & 7;
  int col = ni * 16 + (lane & 15);
  int k = ks * 32 + (lane >> 4) * 8 + j;
  float v = (k < KD) ? W[(size_t)k * 128 + col] : root[(size_t)(k - KD) * 128 + col];
  BtF[idx] = f2bf(v);
}

// FUSED layer: block = 4 waves = 16 nodes. Agg: wave handles its 4 nodes
// SIMULTANEOUSLY (16 lanes/node, lane owns 8 dims, 16B dwordx4 gathers ->
// 16 addresses/edge). Lockstep over max-degree; masked slots v=-2.
// Then barrier, MFMA from LDS (wave = 2 n-frags over 16 rows).
template <int K, int KT, bool FINAL>
__global__ __launch_bounds__(256, 4) void fused_layer(
    const unsigned short* __restrict__ Xc,
    const int* __restrict__ rowptr, const int2* __restrict__ es,
    const unsigned short* __restrict__ BtF,
    const float* __restrict__ bias,
    unsigned short* __restrict__ Hout,
    const float* __restrict__ Wm, const float* __restrict__ bm,
    float* __restrict__ FOut) {
  constexpr int LDK = KT + 8;          // pad keeps rows 16B-aligned, staggers banks
  constexpr int NKS = KT / 32;
  __shared__ unsigned short Asub[16][LDK];
  __shared__ float hred[4][16][2];

  const int w = threadIdx.x >> 6;
  const int lane = threadIdx.x & 63;
  const int lr = lane & 15;
  const int kg = lane >> 4;
  const int node0 = blockIdx.x * 16;

  // ---- agg phase ----
  const int g = lane >> 4;        // node sub-index within wave (0..3)
  const int d16 = lane & 15;      // dim-block: dims d16*8 .. d16*8+7
  const int r = w * 4 + g;        // row in block tile
  const int node = node0 + r;     // N % 16 == 0 (50000/16 exact grid)
  const int beg = rowptr[node];
  const int end = rowptr[node + 1];
  const int deg = end - beg;

  float acc[K][8];
#pragma unroll
  for (int k = 0; k < K; ++k)
#pragma unroll
    for (int j = 0; j < 8; ++j) acc[k][j] = 0.f;

  const int mx = max(max(__shfl(deg, 0), __shfl(deg, 16)),
                     max(__shfl(deg, 32), __shfl(deg, 48)));
  const int lastc = max(end - 1, 0);

  for (int s0 = 0; s0 < mx; s0 += 4) {
    int2 sp[4];
#pragma unroll
    for (int t = 0; t < 4; ++t) sp[t] = es[min(beg + s0 + t, lastc)];
    uint4 rv[4];
#pragma unroll
    for (int t = 0; t < 4; ++t)
      rv[t] = *(const uint4*)(Xc + (size_t)sp[t].x * 128 + d16 * 8);
#pragma unroll
    for (int t = 0; t < 4; ++t) {
      const bool ok = (s0 + t) < deg;
      const float v = ok ? __int_as_float(sp[t].y) * (float)(K - 1) : -2.f;
      float x[8];
      x[0] = __builtin_bit_cast(float, rv[t].x << 16);
      x[1] = __builtin_bit_cast(float, rv[t].x & 0xffff0000u);
      x[2] = __builtin_bit_cast(float, rv[t].y << 16);
      x[3] = __builtin_bit_cast(float, rv[t].y & 0xffff0000u);
      x[4] = __builtin_bit_cast(float, rv[t].z << 16);
      x[5] = __builtin_bit_cast(float, rv[t].z & 0xffff0000u);
      x[6] = __builtin_bit_cast(float, rv[t].w << 16);
      x[7] = __builtin_bit_cast(float, rv[t].w & 0xffff0000u);
#pragma unroll
      for (int k = 0; k < K; ++k) {
        const float wk = fmaxf(1.f - fabsf(v - (float)k), 0.f);
#pragma unroll
        for (int j = 0; j < 8; ++j) acc[k][j] = fmaf(wk, x[j], acc[k][j]);
      }
    }
  }

  const float sc = 1.f / fmaxf((float)deg, 1.f);
#pragma unroll
  for (int k = 0; k < K; ++k) {
    uint4 ov;
    ov.x = (unsigned)f2bf(acc[k][0] * sc) | ((unsigned)f2bf(acc[k][1] * sc) << 16);
    ov.y = (unsigned)f2bf(acc[k][2] * sc) | ((unsigned)f2bf(acc[k][3] * sc) << 16);
    ov.z = (unsigned)f2bf(acc[k][4] * sc) | ((unsigned)f2bf(acc[k][5] * sc) << 16);
    ov.w = (unsigned)f2bf(acc[k][6] * sc) | ((unsigned)f2bf(acc[k][7] * sc) << 16);
    *(uint4*)&Asub[r][k * 128 + d16 * 8] = ov;
  }
  // own row (root term): coalesced 16B copy
  uint4 ownv = *(const uint4*)(Xc + (size_t)node * 128 + d16 * 8);
  *(uint4*)&Asub[r][K * 128 + d16 * 8] = ownv;
  __syncthreads();

  // ---- MFMA phase: wave w owns cols ni0*16 .. +32 (2 n-frags) ----
  const int ni0 = w * 2;
  f32x4 acc2[2];
  acc2[0] = {0.f, 0.f, 0.f, 0.f};
  acc2[1] = {0.f, 0.f, 0.f, 0.f};
#pragma unroll
  for (int ks = 0; ks < NKS; ++ks) {
    bf16x8 a = *(const bf16x8*)&Asub[lr][ks * 32 + kg * 8];
#pragma unroll
    for (int j = 0; j < 2; ++j) {
      bf16x8 b = *(const bf16x8*)(BtF + (size_t)(ks * 8 + ni0 + j) * 512 + lane * 8);
      acc2[j] = __builtin_amdgcn_mfma_f32_16x16x32_bf16(a, b, acc2[j], 0, 0, 0);
    }
  }

  float bv[2];
#pragma unroll
  for (int j = 0; j < 2; ++j) bv[j] = bias[(ni0 + j) * 16 + lr];

  if constexpr (!FINAL) {
#pragma unroll
    for (int rr = 0; rr < 4; ++rr) {
      int row = kg * 4 + rr;
      int onode = node0 + row;
#pragma unroll
      for (int j = 0; j < 2; ++j) {
        float h = elu1(acc2[j][rr] + bv[j]);
        Hout[(size_t)onode * 128 + (ni0 + j) * 16 + lr] = f2bf(h);
      }
    }
  } else {
    float wm0[2], wm1[2];
#pragma unroll
    for (int j = 0; j < 2; ++j) {
      float2 wv = *(const float2*)&Wm[((ni0 + j) * 16 + lr) * 2];
      wm0[j] = wv.x; wm1[j] = wv.y;
    }
#pragma unroll
    for (int rr = 0; rr < 4; ++rr) {
      int row = kg * 4 + rr;
      float t0 = 0.f, t1 = 0.f;
#pragma unroll
      for (int j = 0; j < 2; ++j) {
        float h = elu1(acc2[j][rr] + bv[j]);
        t0 = fmaf(h, wm0[j], t0);
        t1 = fmaf(h, wm1[j], t1);
      }
#pragma unroll
      for (int off = 8; off > 0; off >>= 1) {
        t0 += __shfl_down(t0, off);
        t1 += __shfl_down(t1, off);
      }
      if (lr == 0) {
        hred[w][row][0] = t0;
        hred[w][row][1] = t1;
      }
    }
    __syncthreads();
    if (threadIdx.x < 32) {
      int row = threadIdx.x >> 1;
      int c = threadIdx.x & 1;
      float s = hred[0][row][c] + hred[1][row][c] + hred[2][row][c] +
                hred[3][row][c] + bm[c];
      FOut[(size_t)(node0 + row) * 2 + c] = fmaxf(s, 0.f);
    }
  }
}

extern "C" void kernel_launch(void* const* d_in, const int* in_sizes, int n_in,
                              void* d_out, int out_size, void* d_ws, size_t ws_size,
                              hipStream_t stream) {
  const float* x = (const float*)d_in[0];
  const int* ei = (const int*)d_in[1];
  const float* ea = (const float*)d_in[2];
  const float* W1 = (const float*)d_in[3];
  const float* root1 = (const float*)d_in[4];
  const float* b1 = (const float*)d_in[5];
  const float* W2 = (const float*)d_in[6];
  const float* root2 = (const float*)d_in[7];
  const float* b2 = (const float*)d_in[8];
  const float* Wm = (const float*)d_in[9];
  const float* bm = (const float*)d_in[10];
  const int N = in_sizes[0] / 128;
  const int E = in_sizes[2];
  const int KT1 = 512, KT2 = 768;
  const int nb = cdiv(N, 1024);

  char* base = (char*)d_ws;
  size_t off = 0;
  auto alloc = [&](size_t bytes) -> void* {
    void* p = base + off;
    off += (bytes + 255) & ~(size_t)255;
    return p;
  };
  int* cnt = (int*)alloc((size_t)N * 4);
  int* rowptr = (int*)alloc((size_t)(N + 1) * 4);
  int* cursor = (int*)alloc((size_t)N * 4);
  int* partials = (int*)alloc(256 * 4);
  int* pscan = (int*)alloc(257 * 4);
  int2* es = (int2*)alloc((size_t)E * 8);
  unsigned short* xb = (unsigned short*)alloc((size_t)N * 128 * 2);
  unsigned short* h1 = (unsigned short*)alloc((size_t)N * 128 * 2);
  unsigned short* BtF1 = (unsigned short*)alloc((size_t)128 * KT1 * 2);
  unsigned short* BtF2 = (unsigned short*)alloc((size_t)128 * KT2 * 2);
  (void)ws_size; (void)n_in; (void)out_size;

  // CSR build (dst bins)
  hipMemsetAsync(cnt, 0, (size_t)N * 4, stream);
  hist_kernel<<<cdiv(E, 256), 256, 0, stream>>>(ei, E, cnt);
  scan_partials_kernel<<<nb, 256, 0, stream>>>(cnt, N, partials);
  scan_pscan_kernel<<<1, 256, 0, stream>>>(partials, nb, pscan);
  scan_apply_kernel<<<nb, 256, 0, stream>>>(cnt, N, pscan, nb, rowptr, cursor);
  scatter_kernel<<<cdiv(E, 256), 256, 0, stream>>>(ei, ea, E, cursor, es);

  // weights -> fragment-order bf16
  build_btf_kernel<<<cdiv(128 * KT1, 256), 256, 0, stream>>>(W1, root1, BtF1, 384, KT1);
  build_btf_kernel<<<cdiv(128 * KT2, 256), 256, 0, stream>>>(W2, root2, BtF2, 640, KT2);

  // x -> compact bf16 xb
  cvt_x_kernel<<<2048, 256, 0, stream>>>(x, xb, N * 32);

  const int nblk = N / 16;  // 50000/16 = 3125 exact
  // layer 1 (K=3): fused agg+GEMM -> compact h1
  fused_layer<3, 512, false><<<nblk, 256, 0, stream>>>(
      xb, rowptr, es, BtF1, b1, h1, nullptr, nullptr, nullptr);
  // layer 2 (K=5): fused agg+GEMM+head -> out
  fused_layer<5, 768, true><<<nblk, 256, 0, stream>>>(
      h1, rowptr, es, BtF2, b2, nullptr, Wm, bm, (float*)d_out);
}

// Round 22
// 156.678 us; speedup vs baseline: 3.1611x; 1.0461x over previous
//
#include <hip/hip_runtime.h>
#include <cmath>

// SplineNet: 2x SplineConv(D=128, deg-1 B-spline, 1-D pseudo) + linear head.
// Round 22: r15 fused structure (best 164us, untouched) + aux-chain launch
// fusion: {hist, cvt_x, build_btf1, build_btf2} are mutually independent ->
// ONE block-range-partitioned kernel (11 -> 8 dispatches).

typedef __attribute__((ext_vector_type(8))) short bf16x8;
typedef __attribute__((ext_vector_type(4))) float f32x4;

static inline int cdiv(int a, int b) { return (a + b - 1) / b; }

__device__ __forceinline__ float bf2f(unsigned short u) {
  unsigned v = ((unsigned)u) << 16;
  return __builtin_bit_cast(float, v);
}
__device__ __forceinline__ unsigned short f2bf(float f) {
  unsigned u = __builtin_bit_cast(unsigned, f);
  u += 0x7FFFu + ((u >> 16) & 1u);
  return (unsigned short)(u >> 16);
}
__device__ __forceinline__ float elu1(float v) {
  return v > 0.f ? v : (expf(v) - 1.f);
}

// ---- merged independent aux work, partitioned by block range ----
// [0, nbh): hist (cnt[dst]++)  |  [nbh, nbh+nbc): cvt_x grid-stride
// [nbh+nbc, +nb1): build BtF1  |  rest: build BtF2
__device__ __forceinline__ void btf_build(const float* __restrict__ W,
                                          const float* __restrict__ root,
                                          unsigned short* __restrict__ BtF,
                                          int KD, int idx) {
  int G = idx >> 9;
  int r = idx & 511;
  int lane = r >> 3;
  int j = r & 7;
  int ks = G >> 3;
  int ni = G & 7;
  int col = ni * 16 + (lane & 15);
  int k = ks * 32 + (lane >> 4) * 8 + j;
  float v = (k < KD) ? W[(size_t)k * 128 + col] : root[(size_t)(k - KD) * 128 + col];
  BtF[idx] = f2bf(v);
}

__global__ void aux_fused_kernel(
    const int* __restrict__ ei, const float* __restrict__ ea, int E,
    int* __restrict__ cnt,
    const float* __restrict__ x, unsigned short* __restrict__ xb, int n4,
    const float* __restrict__ W1, const float* __restrict__ root1,
    unsigned short* __restrict__ BtF1,
    const float* __restrict__ W2, const float* __restrict__ root2,
    unsigned short* __restrict__ BtF2,
    int nbh, int nbc, int nb1, int nb2) {
  const int b = blockIdx.x;
  if (b < nbh) {
    int e = b * 256 + threadIdx.x;
    if (e < E) atomicAdd(&cnt[ei[E + e]], 1);
  } else if (b < nbh + nbc) {
    for (int i = (b - nbh) * 256 + threadIdx.x; i < n4; i += nbc * 256) {
      float4 v = ((const float4*)x)[i];
      ushort4 o;
      o.x = f2bf(v.x); o.y = f2bf(v.y); o.z = f2bf(v.z); o.w = f2bf(v.w);
      ((ushort4*)xb)[i] = o;
    }
  } else if (b < nbh + nbc + nb1) {
    int idx = (b - nbh - nbc) * 256 + threadIdx.x;
    if (idx < 128 * 512) btf_build(W1, root1, BtF1, 384, idx);
  } else {
    int idx = (b - nbh - nbc - nb1) * 256 + threadIdx.x;
    if (idx < 128 * 768) btf_build(W2, root2, BtF2, 640, idx);
  }
  (void)ea; (void)nb2;
}

// ---- three-phase device-wide exclusive scan over cnt[N] ----
__global__ void scan_partials_kernel(const int* __restrict__ cnt, int N,
                                     int* __restrict__ partials) {
  __shared__ int red[256];
  int base = blockIdx.x * 1024;
  int s = 0;
  for (int i = threadIdx.x; i < 1024; i += 256) {
    int idx = base + i;
    if (idx < N) s += cnt[idx];
  }
  red[threadIdx.x] = s;
  __syncthreads();
  for (int off = 128; off > 0; off >>= 1) {
    if (threadIdx.x < off) red[threadIdx.x] += red[threadIdx.x + off];
    __syncthreads();
  }
  if (threadIdx.x == 0) partials[blockIdx.x] = red[0];
}

__global__ void scan_pscan_kernel(const int* __restrict__ partials, int nb,
                                  int* __restrict__ pscan) {
  __shared__ int tmp[256];
  int t = threadIdx.x;
  int v = (t < nb) ? partials[t] : 0;
  tmp[t] = v;
  __syncthreads();
  for (int off = 1; off < 256; off <<= 1) {
    int u = (t >= off) ? tmp[t - off] : 0;
    __syncthreads();
    tmp[t] += u;
    __syncthreads();
  }
  pscan[t + 1] = tmp[t];
  if (t == 0) pscan[0] = 0;
}

__global__ void scan_apply_kernel(const int* __restrict__ cnt, int N,
                                  const int* __restrict__ pscan, int nb,
                                  int* __restrict__ rowptr, int* __restrict__ cursor) {
  __shared__ int tsum[256];
  int t = threadIdx.x;
  int base = blockIdx.x * 1024 + t * 4;
  int v0 = 0, v1 = 0, v2 = 0, v3 = 0;
  if (base + 0 < N) v0 = cnt[base + 0];
  if (base + 1 < N) v1 = cnt[base + 1];
  if (base + 2 < N) v2 = cnt[base + 2];
  if (base + 3 < N) v3 = cnt[base + 3];
  int s = v0 + v1 + v2 + v3;
  tsum[t] = s;
  __syncthreads();
  for (int off = 1; off < 256; off <<= 1) {
    int u = (t >= off) ? tsum[t - off] : 0;
    __syncthreads();
    tsum[t] += u;
    __syncthreads();
  }
  int excl = pscan[blockIdx.x] + tsum[t] - s;
  if (base + 0 < N) { rowptr[base + 0] = excl; cursor[base + 0] = excl; excl += v0; }
  if (base + 1 < N) { rowptr[base + 1] = excl; cursor[base + 1] = excl; excl += v1; }
  if (base + 2 < N) { rowptr[base + 2] = excl; cursor[base + 2] = excl; excl += v2; }
  if (base + 3 < N) { rowptr[base + 3] = excl; cursor[base + 3] = excl; excl += v3; }
  if (blockIdx.x == 0 && t == 0) rowptr[N] = pscan[nb];
}

// scatter edges into CSR order; pack (src, p) as int2
__global__ void scatter_kernel(const int* __restrict__ ei,
                               const float* __restrict__ ea, int E,
                               int* __restrict__ cursor, int2* __restrict__ es) {
  int e = blockIdx.x * blockDim.x + threadIdx.x;
  if (e < E) {
    int dst = ei[E + e];
    int pos = atomicAdd(&cursor[dst], 1);
    es[pos] = make_int2(ei[e], __float_as_int(ea[e]));
  }
}

// FUSED layer (r15): block = 4 waves = 16 nodes. Agg: wave handles its 4
// nodes SIMULTANEOUSLY (16 lanes/node, lane owns 8 dims, 16B dwordx4
// gathers -> 16 addresses/edge). Lockstep over max-degree; masked v=-2.
// Then barrier, MFMA from LDS (wave = 2 n-frags over 16 rows).
template <int K, int KT, bool FINAL>
__global__ __launch_bounds__(256, 4) void fused_layer(
    const unsigned short* __restrict__ Xc,
    const int* __restrict__ rowptr, const int2* __restrict__ es,
    const unsigned short* __restrict__ BtF,
    const float* __restrict__ bias,
    unsigned short* __restrict__ Hout,
    const float* __restrict__ Wm, const float* __restrict__ bm,
    float* __restrict__ FOut) {
  constexpr int LDK = KT + 8;          // pad keeps rows 16B-aligned, staggers banks
  constexpr int NKS = KT / 32;
  __shared__ unsigned short Asub[16][LDK];
  __shared__ float hred[4][16][2];

  const int w = threadIdx.x >> 6;
  const int lane = threadIdx.x & 63;
  const int lr = lane & 15;
  const int kg = lane >> 4;
  const int node0 = blockIdx.x * 16;

  // ---- agg phase ----
  const int g = lane >> 4;        // node sub-index within wave (0..3)
  const int d16 = lane & 15;      // dim-block: dims d16*8 .. d16*8+7
  const int r = w * 4 + g;        // row in block tile
  const int node = node0 + r;     // N % 16 == 0 (50000/16 exact grid)
  const int beg = rowptr[node];
  const int end = rowptr[node + 1];
  const int deg = end - beg;

  float acc[K][8];
#pragma unroll
  for (int k = 0; k < K; ++k)
#pragma unroll
    for (int j = 0; j < 8; ++j) acc[k][j] = 0.f;

  const int mx = max(max(__shfl(deg, 0), __shfl(deg, 16)),
                     max(__shfl(deg, 32), __shfl(deg, 48)));
  const int lastc = max(end - 1, 0);

  for (int s0 = 0; s0 < mx; s0 += 4) {
    int2 sp[4];
#pragma unroll
    for (int t = 0; t < 4; ++t) sp[t] = es[min(beg + s0 + t, lastc)];
    uint4 rv[4];
#pragma unroll
    for (int t = 0; t < 4; ++t)
      rv[t] = *(const uint4*)(Xc + (size_t)sp[t].x * 128 + d16 * 8);
#pragma unroll
    for (int t = 0; t < 4; ++t) {
      const bool ok = (s0 + t) < deg;
      const float v = ok ? __int_as_float(sp[t].y) * (float)(K - 1) : -2.f;
      float x[8];
      x[0] = __builtin_bit_cast(float, rv[t].x << 16);
      x[1] = __builtin_bit_cast(float, rv[t].x & 0xffff0000u);
      x[2] = __builtin_bit_cast(float, rv[t].y << 16);
      x[3] = __builtin_bit_cast(float, rv[t].y & 0xffff0000u);
      x[4] = __builtin_bit_cast(float, rv[t].z << 16);
      x[5] = __builtin_bit_cast(float, rv[t].z & 0xffff0000u);
      x[6] = __builtin_bit_cast(float, rv[t].w << 16);
      x[7] = __builtin_bit_cast(float, rv[t].w & 0xffff0000u);
#pragma unroll
      for (int k = 0; k < K; ++k) {
        const float wk = fmaxf(1.f - fabsf(v - (float)k), 0.f);
#pragma unroll
        for (int j = 0; j < 8; ++j) acc[k][j] = fmaf(wk, x[j], acc[k][j]);
      }
    }
  }

  const float sc = 1.f / fmaxf((float)deg, 1.f);
#pragma unroll
  for (int k = 0; k < K; ++k) {
    uint4 ov;
    ov.x = (unsigned)f2bf(acc[k][0] * sc) | ((unsigned)f2bf(acc[k][1] * sc) << 16);
    ov.y = (unsigned)f2bf(acc[k][2] * sc) | ((unsigned)f2bf(acc[k][3] * sc) << 16);
    ov.z = (unsigned)f2bf(acc[k][4] * sc) | ((unsigned)f2bf(acc[k][5] * sc) << 16);
    ov.w = (unsigned)f2bf(acc[k][6] * sc) | ((unsigned)f2bf(acc[k][7] * sc) << 16);
    *(uint4*)&Asub[r][k * 128 + d16 * 8] = ov;
  }
  // own row (root term): coalesced 16B copy
  uint4 ownv = *(const uint4*)(Xc + (size_t)node * 128 + d16 * 8);
  *(uint4*)&Asub[r][K * 128 + d16 * 8] = ownv;
  __syncthreads();

  // ---- MFMA phase: wave w owns cols ni0*16 .. +32 (2 n-frags) ----
  const int ni0 = w * 2;
  f32x4 acc2[2];
  acc2[0] = {0.f, 0.f, 0.f, 0.f};
  acc2[1] = {0.f, 0.f, 0.f, 0.f};
#pragma unroll
  for (int ks = 0; ks < NKS; ++ks) {
    bf16x8 a = *(const bf16x8*)&Asub[lr][ks * 32 + kg * 8];
#pragma unroll
    for (int j = 0; j < 2; ++j) {
      bf16x8 b = *(const bf16x8*)(BtF + (size_t)(ks * 8 + ni0 + j) * 512 + lane * 8);
      acc2[j] = __builtin_amdgcn_mfma_f32_16x16x32_bf16(a, b, acc2[j], 0, 0, 0);
    }
  }

  float bv[2];
#pragma unroll
  for (int j = 0; j < 2; ++j) bv[j] = bias[(ni0 + j) * 16 + lr];

  if constexpr (!FINAL) {
#pragma unroll
    for (int rr = 0; rr < 4; ++rr) {
      int row = kg * 4 + rr;
      int onode = node0 + row;
#pragma unroll
      for (int j = 0; j < 2; ++j) {
        float h = elu1(acc2[j][rr] + bv[j]);
        Hout[(size_t)onode * 128 + (ni0 + j) * 16 + lr] = f2bf(h);
      }
    }
  } else {
    float wm0[2], wm1[2];
#pragma unroll
    for (int j = 0; j < 2; ++j) {
      float2 wv = *(const float2*)&Wm[((ni0 + j) * 16 + lr) * 2];
      wm0[j] = wv.x; wm1[j] = wv.y;
    }
#pragma unroll
    for (int rr = 0; rr < 4; ++rr) {
      int row = kg * 4 + rr;
      float t0 = 0.f, t1 = 0.f;
#pragma unroll
      for (int j = 0; j < 2; ++j) {
        float h = elu1(acc2[j][rr] + bv[j]);
        t0 = fmaf(h, wm0[j], t0);
        t1 = fmaf(h, wm1[j], t1);
      }
#pragma unroll
      for (int off = 8; off > 0; off >>= 1) {
        t0 += __shfl_down(t0, off);
        t1 += __shfl_down(t1, off);
      }
      if (lr == 0) {
        hred[w][row][0] = t0;
        hred[w][row][1] = t1;
      }
    }
    __syncthreads();
    if (threadIdx.x < 32) {
      int row = threadIdx.x >> 1;
      int c = threadIdx.x & 1;
      float s = hred[0][row][c] + hred[1][row][c] + hred[2][row][c] +
                hred[3][row][c] + bm[c];
      FOut[(size_t)(node0 + row) * 2 + c] = fmaxf(s, 0.f);
    }
  }
}

extern "C" void kernel_launch(void* const* d_in, const int* in_sizes, int n_in,
                              void* d_out, int out_size, void* d_ws, size_t ws_size,
                              hipStream_t stream) {
  const float* x = (const float*)d_in[0];
  const int* ei = (const int*)d_in[1];
  const float* ea = (const float*)d_in[2];
  const float* W1 = (const float*)d_in[3];
  const float* root1 = (const float*)d_in[4];
  const float* b1 = (const float*)d_in[5];
  const float* W2 = (const float*)d_in[6];
  const float* root2 = (const float*)d_in[7];
  const float* b2 = (const float*)d_in[8];
  const float* Wm = (const float*)d_in[9];
  const float* bm = (const float*)d_in[10];
  const int N = in_sizes[0] / 128;
  const int E = in_sizes[2];
  const int KT1 = 512, KT2 = 768;
  const int nb = cdiv(N, 1024);

  char* base = (char*)d_ws;
  size_t off = 0;
  auto alloc = [&](size_t bytes) -> void* {
    void* p = base + off;
    off += (bytes + 255) & ~(size_t)255;
    return p;
  };
  int* cnt = (int*)alloc((size_t)N * 4);
  int* rowptr = (int*)alloc((size_t)(N + 1) * 4);
  int* cursor = (int*)alloc((size_t)N * 4);
  int* partials = (int*)alloc(256 * 4);
  int* pscan = (int*)alloc(257 * 4);
  int2* es = (int2*)alloc((size_t)E * 8);
  unsigned short* xb = (unsigned short*)alloc((size_t)N * 128 * 2);
  unsigned short* h1 = (unsigned short*)alloc((size_t)N * 128 * 2);
  unsigned short* BtF1 = (unsigned short*)alloc((size_t)128 * KT1 * 2);
  unsigned short* BtF2 = (unsigned short*)alloc((size_t)128 * KT2 * 2);
  (void)ws_size; (void)n_in; (void)out_size;

  // merged aux: hist + cvt_x + btf1 + btf2 in one dispatch (after memset)
  const int nbh = cdiv(E, 256);
  const int nbc = 1024;
  const int nb1 = cdiv(128 * KT1, 256);
  const int nb2 = cdiv(128 * KT2, 256);
  hipMemsetAsync(cnt, 0, (size_t)N * 4, stream);
  aux_fused_kernel<<<nbh + nbc + nb1 + nb2, 256, 0, stream>>>(
      ei, ea, E, cnt, x, xb, N * 32, W1, root1, BtF1, W2, root2, BtF2,
      nbh, nbc, nb1, nb2);

  // CSR scan + scatter
  scan_partials_kernel<<<nb, 256, 0, stream>>>(cnt, N, partials);
  scan_pscan_kernel<<<1, 256, 0, stream>>>(partials, nb, pscan);
  scan_apply_kernel<<<nb, 256, 0, stream>>>(cnt, N, pscan, nb, rowptr, cursor);
  scatter_kernel<<<cdiv(E, 256), 256, 0, stream>>>(ei, ea, E, cursor, es);

  const int nblk = N / 16;  // 50000/16 = 3125 exact
  // layer 1 (K=3): fused agg+GEMM -> compact h1
  fused_layer<3, 512, false><<<nblk, 256, 0, stream>>>(
      xb, rowptr, es, BtF1, b1, h1, nullptr, nullptr, nullptr);
  // layer 2 (K=5): fused agg+GEMM+head -> out
  fused_layer<5, 768, true><<<nblk, 256, 0, stream>>>(
      h1, rowptr, es, BtF2, b2, nullptr, Wm, bm, (float*)d_out);
}